// Round 3
// baseline (465.925 us; speedup 1.0000x reference)
//
#include <hip/hip_runtime.h>

// FourierFeatureMLP fused kernel for MI355X (gfx950). Round 8.
//
// vs round 7 (205 us; MfmaUtil 30%, VALUBusy 40%, Occupancy 21.8%):
// LDS weight staging was NEUTRAL -> L2 BW not the limiter (L1 already
// absorbs intra-block weight re-reads). Real constraint: ~1.75 waves/SIMD
// (launch_bounds(.,2) + 48KB LDS + 2 uneven block rounds) -> no cross-wave
// MFMA/VALU overlap and ~200cy L2 weight-load latency under-covered by
// 1-kt prefetch. Fixes:
//   * revert staging: 32 KB LDS, ZERO barriers (wave-autonomous again)
//   * __launch_bounds__(256,4): 4 blocks/CU -> all 1024 blocks resident
//     in ONE round (no tail), 4 waves/SIMD overlap
//   * 2-kt-deep weight prefetch (3-slot ring, static indices after unroll)
//   * biases pre-scaled (*2/ln2) into f32 table by convert kernel
//
// Layouts (MFMA 16x16x32, learn_hip-verified):
//   A: lane holds A[m=lane&15][k=quad*8+j]   (W fragment)
//   B: lane holds B[k=quad*8+j][n=lane&15]   (h fragment, n = point)
//   D: n(point)=lane&15, m(unit)=quad*4+reg
// Weights fragment-major: frag = ((layer*4+c)*4+mt)*8+kt, 1 KB each,
// addr = frag*1024 + lane*16 -> fully-coalesced b128 loads.

#define HDIM   256
#define NLAYER 8
#define PTSW   32
#define NTHR   256
#define TILE_N 128
#define WHALVES (NLAYER * HDIM * HDIM)

typedef __attribute__((ext_vector_type(8))) _Float16 half8;
typedef __attribute__((ext_vector_type(4))) _Float16 half4;
typedef __attribute__((ext_vector_type(2))) _Float16 half2;
typedef __attribute__((ext_vector_type(4))) float float4v;

__device__ __forceinline__ half2 pk2(float a, float b) {
    return __builtin_bit_cast(half2, __builtin_amdgcn_cvt_pkrtz(a, b));
}

// tanh(acc + b) with pre-scaled bias bK = b * 2/ln2:
// t = acc*K + bK; z = 2^t; r = 1/(1+z); tanh = 1 - 2r. Saturation-safe.
#define TANH_K 2.885390081777927f
__device__ __forceinline__ float fast_tanh_fused(float acc, float bK) {
    float z = __builtin_amdgcn_exp2f(fmaf(acc, TANH_K, bK));
    float r = __builtin_amdgcn_rcpf(z + 1.0f);
    return fmaf(-2.0f, r, 1.0f);
}

// ---- pre-pass: fp32 -> fp16 weights, permuted to FRAGMENT-major order,
// plus pre-scaled f32 bias table bK[layer*256+u] at halfs offset WHALVES.
__global__ void convert_w_kernel(const float* __restrict__ W_in,
                                 const float* __restrict__ W_h,
                                 const float* __restrict__ b_in,
                                 const float* __restrict__ b_h,
                                 _Float16* __restrict__ dst)
{
    const int i = blockIdx.x * blockDim.x + threadIdx.x;   // 0 .. WHALVES-1
    const int j     = i & 7;
    const int lane  = (i >> 3) & 63;
    const int frag  = i >> 9;
    const int kt    = frag & 7;
    const int mt    = (frag >> 3) & 3;
    const int c     = (frag >> 5) & 3;
    const int layer = frag >> 7;
    const int u = c * 64 + mt * 16 + (lane & 15);
    const int k = kt * 32 + (lane >> 4) * 8 + j;
    const float v = (layer == 0) ? W_in[u * HDIM + k]
                                 : W_h[((layer - 1) * HDIM + u) * HDIM + k];
    dst[i] = (_Float16)v;

    if (i < NLAYER * HDIM) {                               // bias table
        float* bk = (float*)(dst + WHALVES);
        const int l = i >> 8, uu = i & 255;
        const float b = (l == 0) ? b_in[uu] : b_h[(l - 1) * HDIM + uu];
        bk[i] = b * TANH_K;
    }
}

// One dense layer for one wave: hin (B-frags, regs) -> hout (B-frags, regs).
// wl = fragment-major weight base for this layer, pre-offset by lane*8.
// bl = pre-scaled bias row for this layer.
__device__ __forceinline__ void layer_step(const _Float16* __restrict__ wl,
                                           const float* __restrict__ bl,
                                           _Float16* __restrict__ lds0,
                                           _Float16* __restrict__ lds1,
                                           const int laneM, const int quad,
                                           const half8 (&hin)[2][8],
                                           half8 (&hout)[2][8])
{
    #pragma unroll
    for (int c = 0; c < 4; ++c) {
        _Float16* __restrict__ lds = (c & 1) ? lds1 : lds0;

        float4v acc[4][2];
        #pragma unroll
        for (int mt = 0; mt < 4; ++mt)
            #pragma unroll
            for (int nt = 0; nt < 2; ++nt)
                acc[mt][nt] = (float4v){0.f, 0.f, 0.f, 0.f};

        // 3-slot ring, 2-kt-deep prefetch; all indices static after unroll
        half8 A[3][4];
        #pragma unroll
        for (int mt = 0; mt < 4; ++mt)
            A[0][mt] = *(const half8*)&wl[(c * 32 + mt * 8 + 0) * 512];
        #pragma unroll
        for (int mt = 0; mt < 4; ++mt)
            A[1][mt] = *(const half8*)&wl[(c * 32 + mt * 8 + 1) * 512];

        #pragma unroll
        for (int kt = 0; kt < 8; ++kt) {
            if (kt < 6) {
                const int s = (kt + 2) % 3;
                #pragma unroll
                for (int mt = 0; mt < 4; ++mt)
                    A[s][mt] = *(const half8*)&wl[(c * 32 + mt * 8 + kt + 2) * 512];
            }
            const int cs = kt % 3;
            #pragma unroll
            for (int mt = 0; mt < 4; ++mt)
                #pragma unroll
                for (int nt = 0; nt < 2; ++nt)
                    acc[mt][nt] = __builtin_amdgcn_mfma_f32_16x16x32_f16(
                        A[cs][mt], hin[nt][kt], acc[mt][nt], 0, 0, 0);
        }

        // epilogue: bias+tanh, pack, wave-private repack through LDS
        float4 bias[4];
        #pragma unroll
        for (int mt = 0; mt < 4; ++mt)
            bias[mt] = *(const float4*)&bl[c * 64 + mt * 16 + quad * 4];

        #pragma unroll
        for (int mt = 0; mt < 4; ++mt) {
            const int c8 = mt * 2 + (quad >> 1);
            #pragma unroll
            for (int nt = 0; nt < 2; ++nt) {
                const int row = nt * 16 + laneM;
                const float v0 = fast_tanh_fused(acc[mt][nt].x, bias[mt].x);
                const float v1 = fast_tanh_fused(acc[mt][nt].y, bias[mt].y);
                const float v2 = fast_tanh_fused(acc[mt][nt].z, bias[mt].z);
                const float v3 = fast_tanh_fused(acc[mt][nt].w, bias[mt].w);
                const half2 lo = pk2(v0, v1);
                const half2 hi = pk2(v2, v3);
                half4 pkv;
                pkv.x = lo.x; pkv.y = lo.y; pkv.z = hi.x; pkv.w = hi.y;
                *(half4*)&lds[row * 64 + ((c8 ^ (row & 7)) << 3) + (quad & 1) * 4] = pkv;
            }
        }
        // read back as B-frags for next layer (same wave: DS is in-order)
        #pragma unroll
        for (int kp = 0; kp < 2; ++kp)
            #pragma unroll
            for (int nt = 0; nt < 2; ++nt) {
                const int row = nt * 16 + laneM;
                const int c8r = (kp * 4 + quad) ^ (row & 7);
                hout[nt][c * 2 + kp] = *(const half8*)&lds[row * 64 + (c8r << 3)];
            }
    }
}

__device__ __forceinline__ float dot8(const half8 h, const float4 wa, const float4 wb) {
    return (float)h[0]*wa.x + (float)h[1]*wa.y + (float)h[2]*wa.z + (float)h[3]*wa.w
         + (float)h[4]*wb.x + (float)h[5]*wb.y + (float)h[6]*wb.z + (float)h[7]*wb.w;
}

__global__ __launch_bounds__(NTHR, 4)
void ffmlp_kernel(const float* __restrict__ tx,
                  const float* __restrict__ Bf,
                  const _Float16* __restrict__ Wall,
                  const float* __restrict__ W_out,
                  const float* __restrict__ b_out,
                  float* __restrict__ out)
{
    // 4 waves x 2 chunk-parity buffers x (32 pts x 64 units) fp16 = 32 KB
    __shared__ __align__(16) _Float16 lbuf[4][2][PTSW * 64];

    const int tid   = threadIdx.x;
    const int wave  = tid >> 6;
    const int lane  = tid & 63;
    const int laneM = lane & 15;
    const int quad  = lane >> 4;
    const int p0    = blockIdx.x * TILE_N + wave * PTSW;

    const float* bK = (const float*)(Wall + WHALVES);

    half8 h0[2][8], h1[2][8];

    // -------- stage 1: Fourier features directly into B-frag registers ----
    // k = kq*32 + quad*8 + j ; kq 0..3 -> sin(f=k), kq+4 -> cos(f=k).
    // sin(2*pi*r) = v_sin(fract(r)) : argument in revolutions.
    {
        const float2* txv = (const float2*)tx;
        const float2* Bv  = (const float2*)Bf;
        #pragma unroll
        for (int nt = 0; nt < 2; ++nt) {
            const float2 t = txv[p0 + nt * 16 + laneM];
            #pragma unroll
            for (int kq = 0; kq < 4; ++kq) {
                const int f0 = kq * 32 + quad * 8;
                half8 s8, c8v;
                #pragma unroll
                for (int jj = 0; jj < 8; jj += 2) {
                    const float2 bA = Bv[f0 + jj];
                    const float2 bB = Bv[f0 + jj + 1];
                    const float r0 = __builtin_amdgcn_fractf(t.x * bA.x + t.y * bA.y);
                    const float r1 = __builtin_amdgcn_fractf(t.x * bB.x + t.y * bB.y);
                    const half2 sp = pk2(__builtin_amdgcn_sinf(r0), __builtin_amdgcn_sinf(r1));
                    const half2 cp = pk2(__builtin_amdgcn_cosf(r0), __builtin_amdgcn_cosf(r1));
                    s8[jj] = sp.x;  s8[jj + 1] = sp.y;
                    c8v[jj] = cp.x; c8v[jj + 1] = cp.y;
                }
                h0[nt][kq]     = s8;
                h0[nt][kq + 4] = c8v;
            }
        }
    }

    // -------- stage 2: 8 dense layers, fully wave-local, NO barriers ------
    _Float16* __restrict__ lds0 = &lbuf[wave][0][0];
    _Float16* __restrict__ lds1 = &lbuf[wave][1][0];
    #pragma unroll 1
    for (int lp = 0; lp < 4; ++lp) {
        const int la = 2 * lp, lb = 2 * lp + 1;
        layer_step(Wall + la * (HDIM * HDIM) + lane * 8, bK + la * HDIM,
                   lds0, lds1, laneM, quad, h0, h1);
        layer_step(Wall + lb * (HDIM * HDIM) + lane * 8, bK + lb * HDIM,
                   lds0, lds1, laneM, quad, h1, h0);
    }

    // -------- stage 3: output matvec from registers ------------------------
    {
        float s0 = 0.f, s1 = 0.f;
        #pragma unroll
        for (int kt = 0; kt < 8; ++kt) {
            const float4 wa = *(const float4*)&W_out[kt * 32 + quad * 8];
            const float4 wb = *(const float4*)&W_out[kt * 32 + quad * 8 + 4];
            s0 += dot8(h0[0][kt], wa, wb);
            s1 += dot8(h0[1][kt], wa, wb);
        }
        s0 += __shfl_xor(s0, 16); s0 += __shfl_xor(s0, 32);
        s1 += __shfl_xor(s1, 16); s1 += __shfl_xor(s1, 32);
        if (quad == 0) {
            const float bo = b_out[0];
            out[p0 + laneM]      = s0 + bo;
            out[p0 + 16 + laneM] = s1 + bo;
        }
    }
}

extern "C" void kernel_launch(void* const* d_in, const int* in_sizes, int n_in,
                              void* d_out, int out_size, void* d_ws, size_t ws_size,
                              hipStream_t stream) {
    const float* tx    = (const float*)d_in[0];
    const float* Bf    = (const float*)d_in[1];
    const float* W_in  = (const float*)d_in[2];
    const float* b_in  = (const float*)d_in[3];
    const float* W_h   = (const float*)d_in[4];
    const float* b_h   = (const float*)d_in[5];
    const float* W_out = (const float*)d_in[6];
    const float* b_out = (const float*)d_in[7];
    float* out = (float*)d_out;

    _Float16* Wall = (_Float16*)d_ws;   // 1 MiB weights + 8 KB bias table

    const int npts   = in_sizes[0] / 2;
    const int blocks = npts / TILE_N;   // 1024 = 4 per CU, single round

    convert_w_kernel<<<WHALVES / NTHR, NTHR, 0, stream>>>(W_in, W_h, b_in, b_h, Wall);
    ffmlp_kernel<<<blocks, NTHR, 0, stream>>>(tx, Bf, Wall, W_out, b_out, out);
}

// Round 4
// 237.331 us; speedup vs baseline: 1.9632x; 1.9632x over previous
//
#include <hip/hip_runtime.h>

// FourierFeatureMLP fused kernel for MI355X (gfx950). Round 9.
//
// vs round 8 (466 us REGRESSION): launch_bounds(.,4) capped regs at 128 <
// the 128-VGPR h-state -> scratch spill (1.36 GB HBM/dispatch). h-in-regs
// design is pinned at 2 waves/SIMD; occupancy is NOT the lever. Reverted.
// vs round 6 (202 us; MfmaUtil 29, VALUBusy 41): pipes under-overlapped
// because of per-wave program order: [dense MFMA K-loop] -> [dense tanh
// epilogue]. A wave only spends ~1 issue-cyc per ~5-cyc MFMA, so its
// issue port is ~80% idle in the K-loop. Fix: T15-style in-wave pipeline.
// Epilogue of chunk c is independent of K-loop of chunk c+1 -> interleave
// one mt-slice of prev-chunk epilogue into each kt iteration (slices at
// kt=0..3, repack ds_reads at kt=4..5). Carried across layers: chunk 3
// drains inside next layer's chunk 0, producing hin[6],[7] just-in-time
// for kt=6,7 (DS in-order + compiler lgkm deps). acc ping-pongs A/B
// (static names). Bias pre-scaled (*2/ln2) by convert kernel.
//
// Layouts (MFMA 16x16x32, learn_hip-verified):
//   A: lane holds A[m=lane&15][k=quad*8+j]   (W fragment)
//   B: lane holds B[k=quad*8+j][n=lane&15]   (h fragment, n = point)
//   D: n(point)=lane&15, m(unit)=quad*4+reg
// Weights fragment-major: frag = ((layer*4+c)*4+mt)*8+kt, 1 KB each,
// addr = frag*1024 + lane*16 -> fully-coalesced b128 loads.
// Epilogue frag mapping: CE -> next-layer h frags {2*CE, 2*CE+1}.

#define HDIM   256
#define NLAYER 8
#define PTSW   32
#define NTHR   256
#define TILE_N 128
#define WHALVES (NLAYER * HDIM * HDIM)

typedef __attribute__((ext_vector_type(8))) _Float16 half8;
typedef __attribute__((ext_vector_type(4))) _Float16 half4;
typedef __attribute__((ext_vector_type(2))) _Float16 half2;
typedef __attribute__((ext_vector_type(4))) float float4v;

__device__ __forceinline__ half2 pk2(float a, float b) {
    return __builtin_bit_cast(half2, __builtin_amdgcn_cvt_pkrtz(a, b));
}

// tanh(acc + b) with pre-scaled bias bK = b * 2/ln2:
// t = acc*K + bK; z = 2^t; r = 1/(1+z); tanh = 1 - 2r. Saturation-safe.
#define TANH_K 2.885390081777927f
__device__ __forceinline__ float fast_tanh_fused(float acc, float bK) {
    float z = __builtin_amdgcn_exp2f(fmaf(acc, TANH_K, bK));
    float r = __builtin_amdgcn_rcpf(z + 1.0f);
    return fmaf(-2.0f, r, 1.0f);
}

// ---- pre-pass: fp32 -> fp16 weights, permuted to FRAGMENT-major order,
// plus pre-scaled f32 bias table bK[layer*256+u] at halfs offset WHALVES.
__global__ void convert_w_kernel(const float* __restrict__ W_in,
                                 const float* __restrict__ W_h,
                                 const float* __restrict__ b_in,
                                 const float* __restrict__ b_h,
                                 _Float16* __restrict__ dst)
{
    const int i = blockIdx.x * blockDim.x + threadIdx.x;   // 0 .. WHALVES-1
    const int j     = i & 7;
    const int lane  = (i >> 3) & 63;
    const int frag  = i >> 9;
    const int kt    = frag & 7;
    const int mt    = (frag >> 3) & 3;
    const int c     = (frag >> 5) & 3;
    const int layer = frag >> 7;
    const int u = c * 64 + mt * 16 + (lane & 15);
    const int k = kt * 32 + (lane >> 4) * 8 + j;
    const float v = (layer == 0) ? W_in[u * HDIM + k]
                                 : W_h[((layer - 1) * HDIM + u) * HDIM + k];
    dst[i] = (_Float16)v;

    if (i < NLAYER * HDIM) {                               // bias table
        float* bk = (float*)(dst + WHALVES);
        const int l = i >> 8, uu = i & 255;
        const float b = (l == 0) ? b_in[uu] : b_h[(l - 1) * HDIM + uu];
        bk[i] = b * TANH_K;
    }
}

// One chunk's K-loop (8 kt, 8 MFMA each) with the PREVIOUS chunk's (CE)
// epilogue interleaved: tanh slices at kt=0..3, repack ds_reads kt=4..5.
// CE==-1: no epilogue (first chunk of layer 0).
template<int C, int CE>
__device__ __forceinline__ void chunk_step(const _Float16* __restrict__ wl,
                                           const float* __restrict__ blE,
                                           _Float16* __restrict__ ldsE,
                                           const int laneM, const int quad,
                                           const half8 (&hin)[2][8],
                                           half8 (&hdst)[2][8],
                                           float4v (&acc)[4][2],
                                           float4v (&accP)[4][2],
                                           half8 (&A)[2][4])
{
    #pragma unroll
    for (int mt = 0; mt < 4; ++mt)
        #pragma unroll
        for (int nt = 0; nt < 2; ++nt)
            acc[mt][nt] = (float4v){0.f, 0.f, 0.f, 0.f};

    #pragma unroll
    for (int kt = 0; kt < 8; ++kt) {
        const int idx = C * 8 + kt;
        // 1-ahead weight prefetch into the opposite ring slot
        if (idx + 1 < 32) {
            const int c2 = (idx + 1) >> 3, k2 = (idx + 1) & 7;
            #pragma unroll
            for (int mt = 0; mt < 4; ++mt)
                A[(idx + 1) & 1][mt] =
                    *(const half8*)&wl[(c2 * 32 + mt * 8 + k2) * 512];
        }
        #pragma unroll
        for (int mt = 0; mt < 4; ++mt)
            #pragma unroll
            for (int nt = 0; nt < 2; ++nt)
                acc[mt][nt] = __builtin_amdgcn_mfma_f32_16x16x32_f16(
                    A[idx & 1][mt], hin[nt][kt], acc[mt][nt], 0, 0, 0);

        if constexpr (CE >= 0) {
            if (kt < 4) {                       // tanh slice mt = kt
                const int mt = kt;
                const float4 b4 = *(const float4*)&blE[CE * 64 + mt * 16 + quad * 4];
                const int c8 = mt * 2 + (quad >> 1);
                #pragma unroll
                for (int nt = 0; nt < 2; ++nt) {
                    const int row = nt * 16 + laneM;
                    const float v0 = fast_tanh_fused(accP[mt][nt].x, b4.x);
                    const float v1 = fast_tanh_fused(accP[mt][nt].y, b4.y);
                    const float v2 = fast_tanh_fused(accP[mt][nt].z, b4.z);
                    const float v3 = fast_tanh_fused(accP[mt][nt].w, b4.w);
                    const half2 lo = pk2(v0, v1);
                    const half2 hi = pk2(v2, v3);
                    half4 pkv;
                    pkv.x = lo.x; pkv.y = lo.y; pkv.z = hi.x; pkv.w = hi.y;
                    *(half4*)&ldsE[row * 64 + ((c8 ^ (row & 7)) << 3) + (quad & 1) * 4] = pkv;
                }
            } else if (kt < 6) {                // repack reads kp = kt-4
                const int kp = kt - 4;
                #pragma unroll
                for (int nt = 0; nt < 2; ++nt) {
                    const int row = nt * 16 + laneM;
                    const int c8r = (kp * 4 + quad) ^ (row & 7);
                    hdst[nt][CE * 2 + kp] =
                        *(const half8*)&ldsE[row * 64 + (c8r << 3)];
                }
            }
        }
    }
}

// Standalone drain of the final layer's chunk 3 (CE=3).
__device__ __forceinline__ void tail_epilogue(const float* __restrict__ blE,
                                              _Float16* __restrict__ ldsE,
                                              const int laneM, const int quad,
                                              float4v (&accP)[4][2],
                                              half8 (&hdst)[2][8])
{
    #pragma unroll
    for (int mt = 0; mt < 4; ++mt) {
        const float4 b4 = *(const float4*)&blE[3 * 64 + mt * 16 + quad * 4];
        const int c8 = mt * 2 + (quad >> 1);
        #pragma unroll
        for (int nt = 0; nt < 2; ++nt) {
            const int row = nt * 16 + laneM;
            const float v0 = fast_tanh_fused(accP[mt][nt].x, b4.x);
            const float v1 = fast_tanh_fused(accP[mt][nt].y, b4.y);
            const float v2 = fast_tanh_fused(accP[mt][nt].z, b4.z);
            const float v3 = fast_tanh_fused(accP[mt][nt].w, b4.w);
            const half2 lo = pk2(v0, v1);
            const half2 hi = pk2(v2, v3);
            half4 pkv;
            pkv.x = lo.x; pkv.y = lo.y; pkv.z = hi.x; pkv.w = hi.y;
            *(half4*)&ldsE[row * 64 + ((c8 ^ (row & 7)) << 3) + (quad & 1) * 4] = pkv;
        }
    }
    #pragma unroll
    for (int kp = 0; kp < 2; ++kp)
        #pragma unroll
        for (int nt = 0; nt < 2; ++nt) {
            const int row = nt * 16 + laneM;
            const int c8r = (kp * 4 + quad) ^ (row & 7);
            hdst[nt][6 + kp] = *(const half8*)&ldsE[row * 64 + (c8r << 3)];
        }
}

__device__ __forceinline__ float dot8(const half8 h, const float4 wa, const float4 wb) {
    return (float)h[0]*wa.x + (float)h[1]*wa.y + (float)h[2]*wa.z + (float)h[3]*wa.w
         + (float)h[4]*wb.x + (float)h[5]*wb.y + (float)h[6]*wb.z + (float)h[7]*wb.w;
}

__global__ __launch_bounds__(NTHR, 2)
void ffmlp_kernel(const float* __restrict__ tx,
                  const float* __restrict__ Bf,
                  const _Float16* __restrict__ Wall,
                  const float* __restrict__ W_out,
                  const float* __restrict__ b_out,
                  float* __restrict__ out)
{
    // 4 waves x 2 chunk-parity buffers x (32 pts x 64 units) fp16 = 32 KB
    __shared__ __align__(16) _Float16 lbuf[4][2][PTSW * 64];

    const int tid   = threadIdx.x;
    const int wave  = tid >> 6;
    const int lane  = tid & 63;
    const int laneM = lane & 15;
    const int quad  = lane >> 4;
    const int p0    = blockIdx.x * TILE_N + wave * PTSW;

    const float* bK = (const float*)(Wall + WHALVES);

    half8 h0[2][8], h1[2][8];

    // -------- stage 1: Fourier features directly into B-frag registers ----
    // k = kq*32 + quad*8 + j ; kq 0..3 -> sin(f=k), kq+4 -> cos(f=k).
    // sin(2*pi*r) = v_sin(fract(r)) : argument in revolutions.
    {
        const float2* txv = (const float2*)tx;
        const float2* Bv  = (const float2*)Bf;
        #pragma unroll
        for (int nt = 0; nt < 2; ++nt) {
            const float2 t = txv[p0 + nt * 16 + laneM];
            #pragma unroll
            for (int kq = 0; kq < 4; ++kq) {
                const int f0 = kq * 32 + quad * 8;
                half8 s8, c8v;
                #pragma unroll
                for (int jj = 0; jj < 8; jj += 2) {
                    const float2 bA = Bv[f0 + jj];
                    const float2 bB = Bv[f0 + jj + 1];
                    const float r0 = __builtin_amdgcn_fractf(t.x * bA.x + t.y * bA.y);
                    const float r1 = __builtin_amdgcn_fractf(t.x * bB.x + t.y * bB.y);
                    const half2 sp = pk2(__builtin_amdgcn_sinf(r0), __builtin_amdgcn_sinf(r1));
                    const half2 cp = pk2(__builtin_amdgcn_cosf(r0), __builtin_amdgcn_cosf(r1));
                    s8[jj] = sp.x;  s8[jj + 1] = sp.y;
                    c8v[jj] = cp.x; c8v[jj + 1] = cp.y;
                }
                h0[nt][kq]     = s8;
                h0[nt][kq + 4] = c8v;
            }
        }
    }

    // -------- stage 2: 8 dense layers, wave-local, NO barriers,
    //          prev-chunk epilogue pipelined into current chunk's K-loop --
    _Float16* __restrict__ lds0 = &lbuf[wave][0][0];
    _Float16* __restrict__ lds1 = &lbuf[wave][1][0];

    half8  A[2][4];
    float4v accA[4][2], accB[4][2];

    #pragma unroll 1
    for (int lp = 0; lp < 4; ++lp) {
        const int la = 2 * lp, lb = 2 * lp + 1;
        const _Float16* wla = Wall + la * (HDIM * HDIM) + lane * 8;
        const _Float16* wlb = Wall + lb * (HDIM * HDIM) + lane * 8;
        const float* bla = bK + la * HDIM;
        const float* blb = bK + lb * HDIM;
        const float* blp = bK + (la - 1) * HDIM;   // prev layer (lp>0 only)

        // ---- even layer: h0 -> h1 ----
        #pragma unroll
        for (int mt = 0; mt < 4; ++mt) {           // prologue: kt0, kt1
            A[0][mt] = *(const half8*)&wla[(mt * 8 + 0) * 512];
            A[1][mt] = *(const half8*)&wla[(mt * 8 + 1) * 512];
        }
        if (lp == 0)
            chunk_step<0, -1>(wla, bla, lds1, laneM, quad, h0, h0, accA, accB, A);
        else
            chunk_step<0, 3>(wla, blp, lds1, laneM, quad, h0, h0, accA, accB, A);
        chunk_step<1, 0>(wla, bla, lds0, laneM, quad, h0, h1, accB, accA, A);
        chunk_step<2, 1>(wla, bla, lds1, laneM, quad, h0, h1, accA, accB, A);
        chunk_step<3, 2>(wla, bla, lds0, laneM, quad, h0, h1, accB, accA, A);

        // ---- odd layer: h1 -> h0 (chunk0 drains even layer's chunk3) ----
        #pragma unroll
        for (int mt = 0; mt < 4; ++mt) {
            A[0][mt] = *(const half8*)&wlb[(mt * 8 + 0) * 512];
            A[1][mt] = *(const half8*)&wlb[(mt * 8 + 1) * 512];
        }
        chunk_step<0, 3>(wlb, bla, lds1, laneM, quad, h1, h1, accA, accB, A);
        chunk_step<1, 0>(wlb, blb, lds0, laneM, quad, h1, h0, accB, accA, A);
        chunk_step<2, 1>(wlb, blb, lds1, laneM, quad, h1, h0, accA, accB, A);
        chunk_step<3, 2>(wlb, blb, lds0, laneM, quad, h1, h0, accB, accA, A);
    }
    // drain final layer's chunk 3 into h0[*][6],[7]
    tail_epilogue(bK + 7 * HDIM, lds1, laneM, quad, accB, h0);

    // -------- stage 3: output matvec from registers ------------------------
    {
        float s0 = 0.f, s1 = 0.f;
        #pragma unroll
        for (int kt = 0; kt < 8; ++kt) {
            const float4 wa = *(const float4*)&W_out[kt * 32 + quad * 8];
            const float4 wb = *(const float4*)&W_out[kt * 32 + quad * 8 + 4];
            s0 += dot8(h0[0][kt], wa, wb);
            s1 += dot8(h0[1][kt], wa, wb);
        }
        s0 += __shfl_xor(s0, 16); s0 += __shfl_xor(s0, 32);
        s1 += __shfl_xor(s1, 16); s1 += __shfl_xor(s1, 32);
        if (quad == 0) {
            const float bo = b_out[0];
            out[p0 + laneM]      = s0 + bo;
            out[p0 + 16 + laneM] = s1 + bo;
        }
    }
}

extern "C" void kernel_launch(void* const* d_in, const int* in_sizes, int n_in,
                              void* d_out, int out_size, void* d_ws, size_t ws_size,
                              hipStream_t stream) {
    const float* tx    = (const float*)d_in[0];
    const float* Bf    = (const float*)d_in[1];
    const float* W_in  = (const float*)d_in[2];
    const float* b_in  = (const float*)d_in[3];
    const float* W_h   = (const float*)d_in[4];
    const float* b_h   = (const float*)d_in[5];
    const float* W_out = (const float*)d_in[6];
    const float* b_out = (const float*)d_in[7];
    float* out = (float*)d_out;

    _Float16* Wall = (_Float16*)d_ws;   // 1 MiB weights + 8 KB bias table

    const int npts   = in_sizes[0] / 2;
    const int blocks = npts / TILE_N;   // 1024

    convert_w_kernel<<<WHALVES / NTHR, NTHR, 0, stream>>>(W_in, W_h, b_in, b_h, Wall);
    ffmlp_kernel<<<blocks, NTHR, 0, stream>>>(tx, Bf, Wall, W_out, b_out, out);
}